// Round 5
// baseline (658.408 us; speedup 1.0000x reference)
//
#include <hip/hip_runtime.h>
#include <hip/hip_bf16.h>

#define B_ 8
#define T_ 256
#define U_ 64
#define D_ 512
#define V_ 1024
#define M_ (B_*T_*U_)   // 131072

typedef __attribute__((ext_vector_type(8))) short bf16x8;
typedef __attribute__((ext_vector_type(4))) float f32x4;

__device__ __forceinline__ void gld_lds16(const void* g, void* l) {
    __builtin_amdgcn_global_load_lds(
        (const __attribute__((address_space(1))) void*)g,
        (__attribute__((address_space(3))) void*)l, 16, 0, 0);
}

// Convert W (V x D fp32, row-major) into bf16, pre-tiled k-major for 128-wide
// N-tiles: Wt[((tileN*64 + k8)*128 + nl)*8 + e] = W[(tileN*128+nl)*512 + k8*8 + e]
// Each GEMM K-step's B tile is one contiguous 16 KB chunk whose lane-contiguous
// global_load_lds layout is conflict-free for B-frag reads.
__global__ void prep_kernel(const float* __restrict__ W,
                            const int* __restrict__ slen, const int* __restrict__ tlen,
                            __hip_bfloat16* __restrict__ Wt,
                            float* __restrict__ lenout) {
    int t = blockIdx.x * 256 + threadIdx.x;   // 65536 threads
    int n  = t >> 6;        // 0..1023
    int k8 = t & 63;        // 0..63
    const float4* p = (const float4*)(W + (size_t)n * D_ + k8 * 8);
    float4 a = p[0], c = p[1];
    union { __hip_bfloat16 h[8]; bf16x8 v; } u;
    u.h[0] = __float2bfloat16(a.x); u.h[1] = __float2bfloat16(a.y);
    u.h[2] = __float2bfloat16(a.z); u.h[3] = __float2bfloat16(a.w);
    u.h[4] = __float2bfloat16(c.x); u.h[5] = __float2bfloat16(c.y);
    u.h[6] = __float2bfloat16(c.z); u.h[7] = __float2bfloat16(c.w);
    int j = n >> 7, nl = n & 127;
    *(bf16x8*)(Wt + ((size_t)(j * 64 + k8) * 128 + nl) * 8) = u.v;
    if (blockIdx.x == 0 && threadIdx.x < 8) {
        lenout[threadIdx.x]     = (float)slen[threadIdx.x];
        lenout[8 + threadIdx.x] = (float)tlen[threadIdx.x];
    }
}

__device__ __forceinline__ void relu_store8(__hip_bfloat16* dst,
                                            float4 a, float4 a2, float4 b, float4 b2) {
    union { __hip_bfloat16 h[8]; bf16x8 v; } u;
    u.h[0] = __float2bfloat16(fmaxf(a.x  + b.x,  0.f));
    u.h[1] = __float2bfloat16(fmaxf(a.y  + b.y,  0.f));
    u.h[2] = __float2bfloat16(fmaxf(a.z  + b.z,  0.f));
    u.h[3] = __float2bfloat16(fmaxf(a.w  + b.w,  0.f));
    u.h[4] = __float2bfloat16(fmaxf(a2.x + b2.x, 0.f));
    u.h[5] = __float2bfloat16(fmaxf(a2.y + b2.y, 0.f));
    u.h[6] = __float2bfloat16(fmaxf(a2.z + b2.z, 0.f));
    u.h[7] = __float2bfloat16(fmaxf(a2.w + b2.w, 0.f));
    *(bf16x8*)dst = u.v;
}

// C[M,1024] = relu(src[b,t,:]+tgt[b,u,:]) @ W^T + bias
// 256x128 tile (4 t-rows x 64 u-rows x 128 cols), BK=64, 512 threads = 8 waves
// (4M x 2N), each wave a 64x64 sub-tile (4x4 MFMA frags, acc = 64 VGPR).
// vs r4 (128x256): doubles the M-extent instead of N -> Wt L2-read traffic
// halves again (0.5 GB total), tgt/src/store traffic unchanged, same proven
// 2-barrier K-loop and 0.5 KB-LDS-per-MFMA fragment reuse.
__global__ __launch_bounds__(512, 4) void joiner_gemm(
    const float* __restrict__ src, const float* __restrict__ tgt,
    const __hip_bfloat16* __restrict__ Wt, const float* __restrict__ bias,
    float* __restrict__ out) {
    // A: 256 rows x 64 k, padded stride 72 bf16 (proven conflict-free)
    __shared__ __align__(16) __hip_bfloat16 As[256 * 72];    // 36 KB
    // B: k-major [k8][n=128][8e], matches gld_lds lane-contiguous layout
    __shared__ __align__(16) __hip_bfloat16 Bs[8 * 128 * 8]; // 16 KB

    const int tid = threadIdx.x;
    const int bx  = blockIdx.x;           // 4096 blocks
    const int tileN = bx & 7;
    const int tileM = bx >> 3;            // 0..511
    const int m_base = tileM * 256;
    const int b  = m_base >> 14;          // 16384 % 256 == 0: never straddles b
    const int t0 = (m_base & 16383) >> 6; // block covers t0..t0+3, all 64 u

    // A-staging coords: thread stages rows {j*64 + r0}, j=0..3 (t0+j, u=r0)
    const int r0 = tid >> 3;              // 0..63  (= u)
    const int kc = (tid & 7) * 8;         // 0..56
    const float* srcA = src + (size_t)(b * T_ + t0) * D_ + kc;   // +j*D_ for row j
    const float* tgtA = tgt + (size_t)(b * U_ + r0) * D_ + kc;
    __hip_bfloat16* As0 = As + r0 * 72 + kc;

    const __hip_bfloat16* WtT = Wt + (size_t)tileN * 64 * 128 * 8;

    const int wid  = tid >> 6, lane = tid & 63;
    const int waveM = wid >> 1, waveN = wid & 1;
    const int lrow = lane & 15, lk = lane >> 4;
    const __hip_bfloat16* AsW = As + (waveM * 64 + lrow) * 72 + lk * 8;
    const __hip_bfloat16* BsW = Bs + ((size_t)lk * 128 + waveN * 64 + lrow) * 8;

    f32x4 acc[4][4] = {};

    for (int kk = 0; kk < 8; ++kk) {
        // ---- stage B: 16 KB contiguous chunk via async global->LDS (16 B/lane)
        const __hip_bfloat16* gB = WtT + (size_t)kk * 8192;
        #pragma unroll
        for (int i = 0; i < 2; ++i) {
            const int c = wid * 2 + i;                       // wave-uniform 0..15
            gld_lds16(gB + ((size_t)c * 64 + lane) * 8, (void*)(Bs + c * 512));
        }
        // ---- stage A: relu(src+tgt) -> bf16 -> LDS (10 loads feed 4 rows)
        const int ko = kk * 64;
        float4 g0  = *(const float4*)(tgtA + ko);
        float4 g0b = *(const float4*)(tgtA + ko + 4);
        #pragma unroll
        for (int j = 0; j < 4; ++j) {
            float4 s0  = *(const float4*)(srcA + j * D_ + ko);
            float4 s0b = *(const float4*)(srcA + j * D_ + ko + 4);
            relu_store8(As0 + j * 64 * 72, s0, s0b, g0, g0b);  // row j*64+r0
        }

        __syncthreads();   // drains gld_lds + ds_writes (compiler-inserted cnt)

        #pragma unroll
        for (int ks = 0; ks < 2; ++ks) {
            bf16x8 af[4], bfr[4];
            #pragma unroll
            for (int i = 0; i < 4; ++i)
                af[i] = *(const bf16x8*)(AsW + i * 16 * 72 + ks * 32);
            #pragma unroll
            for (int j = 0; j < 4; ++j)
                bfr[j] = *(const bf16x8*)(BsW + ks * 4096 + j * 128);
            #pragma unroll
            for (int i = 0; i < 4; ++i)
                #pragma unroll
                for (int j = 0; j < 4; ++j)
                    acc[i][j] = __builtin_amdgcn_mfma_f32_16x16x32_bf16(
                        af[i], bfr[j], acc[i][j], 0, 0, 0);
        }
        if (kk != 7) __syncthreads();   // WAR: next kk overwrites As/Bs
    }

    // ---- epilogue: C/D layout col = lane&15, row = (lane>>4)*4 + reg
    const int n0 = tileN * 128 + waveN * 64;
    float bv[4];
    #pragma unroll
    for (int j = 0; j < 4; ++j) bv[j] = bias[n0 + j * 16 + lrow];
    #pragma unroll
    for (int i = 0; i < 4; ++i) {
        const int mrow = m_base + waveM * 64 + i * 16 + lk * 4;
        #pragma unroll
        for (int r = 0; r < 4; ++r) {
            float* orow = out + (size_t)(mrow + r) * V_;
            #pragma unroll
            for (int j = 0; j < 4; ++j)
                orow[n0 + j * 16 + lrow] = acc[i][j][r] + bv[j];
        }
    }
}

extern "C" void kernel_launch(void* const* d_in, const int* in_sizes, int n_in,
                              void* d_out, int out_size, void* d_ws, size_t ws_size,
                              hipStream_t stream) {
    const float* src  = (const float*)d_in[0];
    const int*   slen = (const int*)d_in[1];
    const float* tgt  = (const float*)d_in[2];
    const int*   tlen = (const int*)d_in[3];
    const float* W    = (const float*)d_in[4];
    const float* bias = (const float*)d_in[5];
    float* out = (float*)d_out;
    __hip_bfloat16* Wt = (__hip_bfloat16*)d_ws;   // 1 MB

    prep_kernel<<<256, 256, 0, stream>>>(W, slen, tlen, Wt, out + (size_t)M_ * V_);
    joiner_gemm<<<(M_ / 256) * (V_ / 128), 512, 0, stream>>>(src, tgt, Wt, bias, out);
}